// Round 4
// baseline (3635.232 us; speedup 1.0000x reference)
//
#include <hip/hip_runtime.h>
#include <hip/hip_bf16.h>

#define SELU_LAM   1.0507009873554805f
#define SELU_ALPHA 1.6732632423543772f

// 128 nodes per bucket
#define NBSH 7
#define NPB  128

__device__ __forceinline__ float selu_f(float v) {
    return v > 0.0f ? SELU_LAM * v
                    : (SELU_LAM * SELU_ALPHA) * (expf(v) - 1.0f);
}

__device__ __forceinline__ unsigned bf16r(float f) {   // RNE f32->bf16 bits
    unsigned u = __float_as_uint(f);
    return (u + 0x7FFFu + ((u >> 16) & 1u)) >> 16;
}

// ---------------------------------------------------------------- x -> bf16

__global__ __launch_bounds__(256) void to_bf16(const float4* __restrict__ x,
                                               uint4* __restrict__ xb, int nv) {
    int i = blockIdx.x * 256 + threadIdx.x;     // uint4 index (8 floats)
    if (i >= nv) return;
    float4 a = x[2 * i], b = x[2 * i + 1];
    uint4 o;
    o.x = bf16r(a.x) | (bf16r(a.y) << 16);
    o.y = bf16r(a.z) | (bf16r(a.w) << 16);
    o.z = bf16r(b.x) | (bf16r(b.y) << 16);
    o.w = bf16r(b.z) | (bf16r(b.w) << 16);
    xb[i] = o;
}

// ---------------------------------------------------------------- bucketing

// LDS-privatized bucket histogram (B <= 1024)
__global__ __launch_bounds__(256) void bucket_hist(const int* __restrict__ edst,
                                                   int* __restrict__ bcnt, int E, int B) {
    __shared__ int lc[1024];
    for (int i = threadIdx.x; i < B; i += 256) lc[i] = 0;
    __syncthreads();
    int tid = blockIdx.x * 256 + threadIdx.x;
    int stride = gridDim.x * 256;
    int n4 = E >> 2;
    for (int j = tid; j < n4; j += stride) {
        int4 d = ((const int4*)edst)[j];
        atomicAdd(&lc[d.x >> NBSH], 1);
        atomicAdd(&lc[d.y >> NBSH], 1);
        atomicAdd(&lc[d.z >> NBSH], 1);
        atomicAdd(&lc[d.w >> NBSH], 1);
    }
    for (int j = (n4 << 2) + tid; j < E; j += stride) atomicAdd(&lc[edst[j] >> NBSH], 1);
    __syncthreads();
    for (int i = threadIdx.x; i < B; i += 256) if (lc[i]) atomicAdd(&bcnt[i], lc[i]);
}

// single-block exclusive scan of bucket counts (B <= 1024)
__global__ __launch_bounds__(1024) void bucket_scan(const int* __restrict__ bcnt,
                                                    int* __restrict__ boff,
                                                    int* __restrict__ bfill, int B, int E) {
    __shared__ int buf[1024];
    int t = threadIdx.x;
    buf[t] = (t < B) ? bcnt[t] : 0; __syncthreads();
    for (int d = 1; d < 1024; d <<= 1) {
        int v = (t >= d) ? buf[t - d] : 0; __syncthreads();
        buf[t] += v; __syncthreads();
    }
    if (t < B) {
        int excl = (t == 0) ? 0 : buf[t - 1];
        boff[t] = excl;
        bfill[t] = excl;
    }
    if (t == 0) boff[B] = E;
}

// route edges into bucket regions; desc = (src | dstlow<<17, w-bits)
__global__ __launch_bounds__(256) void bucket_scatter(const int* __restrict__ esrc,
                                                      const int* __restrict__ edst,
                                                      const float* __restrict__ ew,
                                                      int* __restrict__ bfill,
                                                      int2* __restrict__ binned, int E) {
    int tid = blockIdx.x * 256 + threadIdx.x;
    int stride = gridDim.x * 256;
    int n4 = E >> 2;
    for (int j = tid; j < n4; j += stride) {
        int4   s = ((const int4*)esrc)[j];
        int4   d = ((const int4*)edst)[j];
        float4 w = ((const float4*)ew)[j];
        int p;
        p = atomicAdd(&bfill[d.x >> NBSH], 1);
        binned[p] = make_int2(s.x | ((d.x & (NPB - 1)) << 17), __float_as_int(w.x));
        p = atomicAdd(&bfill[d.y >> NBSH], 1);
        binned[p] = make_int2(s.y | ((d.y & (NPB - 1)) << 17), __float_as_int(w.y));
        p = atomicAdd(&bfill[d.z >> NBSH], 1);
        binned[p] = make_int2(s.z | ((d.z & (NPB - 1)) << 17), __float_as_int(w.z));
        p = atomicAdd(&bfill[d.w >> NBSH], 1);
        binned[p] = make_int2(s.w | ((d.w & (NPB - 1)) << 17), __float_as_int(w.w));
    }
    for (int j = (n4 << 2) + tid; j < E; j += stride) {
        int dd = edst[j];
        int p = atomicAdd(&bfill[dd >> NBSH], 1);
        binned[p] = make_int2(esrc[j] | ((dd & (NPB - 1)) << 17), __float_as_int(ew[j]));
    }
}

// one block per bucket: 128-node x 128-float accumulator in LDS; fused residual.
template<bool BF16>
__global__ __launch_bounds__(512) void bucket_gather(const uint* __restrict__ xb,
                                                     const float* __restrict__ x,
                                                     const int* __restrict__ boff,
                                                     const int2* __restrict__ binned,
                                                     float* __restrict__ out, int N) {
    __shared__ float acc[NPB * 128];   // 64 KB
    int b = blockIdx.x;
    int node0 = b << NBSH;

    for (int i = threadIdx.x; i < NPB * 32; i += 512)
        ((float4*)acc)[i] = make_float4(0.f, 0.f, 0.f, 0.f);
    __syncthreads();

    int beg = boff[b], end = boff[b + 1];
    int wid  = threadIdx.x >> 6;
    int lane = threadIdx.x & 63;

    for (int e0 = beg + wid * 4; e0 < end; e0 += 32) {
        // load phase (up to 4 independent edges)
        int   dl[4]; float wv[4]; float v0[4], v1[4]; bool ok[4];
        #pragma unroll
        for (int u = 0; u < 4; ++u) {
            ok[u] = (e0 + u < end);
            if (ok[u]) {
                int2 dd = binned[e0 + u];
                int src = dd.x & 0x1FFFF;
                dl[u] = (dd.x >> 17) & (NPB - 1);
                wv[u] = __int_as_float(dd.y);
                if (BF16) {
                    uint pk = xb[(size_t)src * 64 + lane];
                    v0[u] = __uint_as_float(pk << 16);
                    v1[u] = __uint_as_float(pk & 0xFFFF0000u);
                } else {
                    float2 v = ((const float2*)(x + (size_t)src * 128))[lane];
                    v0[u] = v.x; v1[u] = v.y;
                }
            }
        }
        // accumulate phase
        #pragma unroll
        for (int u = 0; u < 4; ++u) {
            if (ok[u]) {
                atomicAdd(&acc[dl[u] * 128 + lane * 2 + 0], v0[u] * wv[u]);
                atomicAdd(&acc[dl[u] * 128 + lane * 2 + 1], v1[u] * wv[u]);
            }
        }
    }
    __syncthreads();

    // epilogue: out = acc + x (residual), coalesced
    int nnodes = min(NPB, N - node0);
    for (int i = threadIdx.x; i < nnodes * 32; i += 512) {
        int node = node0 + (i >> 5);
        int c4   = i & 31;
        float4 r = ((const float4*)(x + (size_t)node * 128))[c4];
        float4 a = ((float4*)acc)[i];
        ((float4*)(out + (size_t)node * 128))[c4] =
            make_float4(a.x + r.x, a.y + r.y, a.z + r.z, a.w + r.w);
    }
}

// ------------------------------------------------- fallback atomic path

__global__ __launch_bounds__(256) void copy_kernel(const float4* __restrict__ src,
                                                   float4* __restrict__ dst, int n4) {
    int i = blockIdx.x * 256 + threadIdx.x;
    if (i < n4) dst[i] = src[i];
}

__global__ __launch_bounds__(256) void scatter_kernel(const float* __restrict__ x,
                                                      const int* __restrict__ esrc,
                                                      const int* __restrict__ edst,
                                                      const float* __restrict__ ew,
                                                      float* __restrict__ agg, int E) {
    int e = blockIdx.x * 8 + (threadIdx.x >> 5);
    if (e >= E) return;
    int lane = threadIdx.x & 31;
    int s = esrc[e];
    int d = edst[e];
    float w = ew[e];
    float4 v = ((const float4*)(x + (size_t)s * 128))[lane];
    float* dp = agg + (size_t)d * 128 + lane * 4;
    atomicAdd(dp + 0, v.x * w);
    atomicAdd(dp + 1, v.y * w);
    atomicAdd(dp + 2, v.z * w);
    atomicAdd(dp + 3, v.w * w);
}

// ----------------------------------------------------------------- GEMM

// out[r,:] = selu(in[r,:] @ W + b); W [128][128] row-major; in-place safe.
__global__ __launch_bounds__(256) void gemm_bias_selu(const float* __restrict__ inp,
                                                      const float* __restrict__ W,
                                                      const float* __restrict__ bias,
                                                      float* __restrict__ outp, int nrows) {
    __shared__ float sW[128 * 128];
    __shared__ float sH[32 * 128];

    float4* sW4 = (float4*)sW;
    float4* sH4 = (float4*)sH;

    for (int i = threadIdx.x; i < 128 * 32; i += 256)
        sW4[i] = ((const float4*)W)[i];

    int row0 = blockIdx.x * 32;
    for (int i = threadIdx.x; i < 32 * 32; i += 256) {
        int r = row0 + (i >> 5);
        sH4[i] = (r < nrows) ? ((const float4*)inp)[(size_t)r * 32 + (i & 31)]
                             : make_float4(0.f, 0.f, 0.f, 0.f);
    }
    __syncthreads();

    int cg = threadIdx.x & 31;
    int rg = (threadIdx.x >> 5) << 2;

    float4 acc[4];
    #pragma unroll
    for (int r = 0; r < 4; ++r) acc[r] = make_float4(0.f, 0.f, 0.f, 0.f);

    #pragma unroll 4
    for (int k4 = 0; k4 < 32; ++k4) {
        float4 w0 = sW4[(k4 * 4 + 0) * 32 + cg];
        float4 w1 = sW4[(k4 * 4 + 1) * 32 + cg];
        float4 w2 = sW4[(k4 * 4 + 2) * 32 + cg];
        float4 w3 = sW4[(k4 * 4 + 3) * 32 + cg];
        #pragma unroll
        for (int r = 0; r < 4; ++r) {
            float4 h = sH4[(rg + r) * 32 + k4];
            acc[r].x = fmaf(h.x, w0.x, fmaf(h.y, w1.x, fmaf(h.z, w2.x, fmaf(h.w, w3.x, acc[r].x))));
            acc[r].y = fmaf(h.x, w0.y, fmaf(h.y, w1.y, fmaf(h.z, w2.y, fmaf(h.w, w3.y, acc[r].y))));
            acc[r].z = fmaf(h.x, w0.z, fmaf(h.y, w1.z, fmaf(h.z, w2.z, fmaf(h.w, w3.z, acc[r].z))));
            acc[r].w = fmaf(h.x, w0.w, fmaf(h.y, w1.w, fmaf(h.z, w2.w, fmaf(h.w, w3.w, acc[r].w))));
        }
    }

    float4 bv = ((const float4*)bias)[cg];
    #pragma unroll
    for (int r = 0; r < 4; ++r) {
        int row = row0 + rg + r;
        if (row < nrows) {
            float4 o;
            o.x = selu_f(acc[r].x + bv.x);
            o.y = selu_f(acc[r].y + bv.y);
            o.z = selu_f(acc[r].z + bv.z);
            o.w = selu_f(acc[r].w + bv.w);
            ((float4*)outp)[(size_t)row * 32 + cg] = o;
        }
    }
}

// ---------------------------------------------------------------- launch

extern "C" void kernel_launch(void* const* d_in, const int* in_sizes, int n_in,
                              void* d_out, int out_size, void* d_ws, size_t ws_size,
                              hipStream_t stream) {
    (void)n_in; (void)out_size;
    const float* x    = (const float*)d_in[0];
    const int*   esrc = (const int*)  d_in[1];
    const int*   edst = (const int*)  d_in[2];
    const float* ew   = (const float*)d_in[3];
    const float* W1   = (const float*)d_in[4];
    const float* b1   = (const float*)d_in[5];
    const float* W2   = (const float*)d_in[6];
    const float* b2   = (const float*)d_in[7];
    float* out = (float*)d_out;

    int N = in_sizes[0] / 128;
    int E = in_sizes[1];
    int B = (N + NPB - 1) >> NBSH;

    // ws layout: bcnt(B) | boff(B+1) | bfill(B) | [align16] xb(N*128*2B) | binned(E*8B)
    size_t hdr   = ((size_t)(3 * B + 1) * 4 + 15) & ~(size_t)15;
    size_t xb_b  = (size_t)N * 256;
    size_t bin_b = (size_t)E * 8;
    size_t need_bf16 = hdr + xb_b + bin_b;
    size_t need_f32  = hdr + bin_b;

    bool use_bf16 = (ws_size >= need_bf16);
    bool use_csr  = (B <= 1024) && (ws_size >= need_f32) && (N <= 131072);

    if (use_csr) {
        int*  bcnt  = (int*)d_ws;
        int*  boff  = bcnt + B;
        int*  bfill = boff + B + 1;
        uint* xb    = (uint*)((char*)d_ws + hdr);
        int2* binned = (int2*)((char*)d_ws + hdr + (use_bf16 ? xb_b : 0));

        hipMemsetAsync(bcnt, 0, (size_t)B * 4, stream);

        if (use_bf16) {
            int nv = N * 16;   // uint4 count = N*128/8
            to_bf16<<<(nv + 255) / 256, 256, 0, stream>>>((const float4*)x, (uint4*)xb, nv);
        }

        int hb = (E / 4 + 255) / 256; if (hb > 2048) hb = 2048;
        bucket_hist<<<hb, 256, 0, stream>>>(edst, bcnt, E, B);
        bucket_scan<<<1, 1024, 0, stream>>>(bcnt, boff, bfill, B, E);
        bucket_scatter<<<hb, 256, 0, stream>>>(esrc, edst, ew, bfill, binned, E);

        if (use_bf16)
            bucket_gather<true><<<B, 512, 0, stream>>>(xb, x, boff, binned, out, N);
        else
            bucket_gather<false><<<B, 512, 0, stream>>>(xb, x, boff, binned, out, N);
    } else {
        int n4 = N * 32;
        copy_kernel<<<(n4 + 255) / 256, 256, 0, stream>>>((const float4*)x, (float4*)out, n4);
        scatter_kernel<<<(E + 7) / 8, 256, 0, stream>>>(x, esrc, edst, ew, out, E);
    }

    // ---- dense layers, in place ----
    int gblocks = (N + 31) / 32;
    gemm_bias_selu<<<gblocks, 256, 0, stream>>>(out, W1, b1, out, N);
    gemm_bias_selu<<<gblocks, 256, 0, stream>>>(out, W2, b2, out, N);
}

// Round 5
// 3045.510 us; speedup vs baseline: 1.1936x; 1.1936x over previous
//
#include <hip/hip_runtime.h>
#include <hip/hip_bf16.h>

#define SELU_LAM   1.0507009873554805f
#define SELU_ALPHA 1.6732632423543772f

// 64 nodes per bucket
#define NBSH 6
#define NPB  64

__device__ __forceinline__ float selu_f(float v) {
    return v > 0.0f ? SELU_LAM * v
                    : (SELU_LAM * SELU_ALPHA) * (expf(v) - 1.0f);
}

__device__ __forceinline__ unsigned bf16r(float f) {   // RNE f32->bf16 bits
    unsigned u = __float_as_uint(f);
    return (u + 0x7FFFu + ((u >> 16) & 1u)) >> 16;
}

// ------------------------------------------- x -> bf16, deinterleaved pairs
// xb[row*64 + l] = bf16(x[row*128 + l]) | bf16(x[row*128 + l + 64]) << 16

__global__ __launch_bounds__(256) void to_bf16(const float* __restrict__ x,
                                               uint* __restrict__ xb, int total) {
    int i = blockIdx.x * 256 + threadIdx.x;   // one uint each; total = N*64
    if (i >= total) return;
    int row = i >> 6, l = i & 63;
    float a = x[(size_t)row * 128 + l];
    float b = x[(size_t)row * 128 + l + 64];
    xb[i] = bf16r(a) | (bf16r(b) << 16);
}

// ---------------------------------------------------------------- bucketing

// LDS-privatized bucket histogram (B <= 2048)
__global__ __launch_bounds__(256) void bucket_hist(const int* __restrict__ edst,
                                                   int* __restrict__ bcnt, int E, int B) {
    __shared__ int lc[2048];
    for (int i = threadIdx.x; i < B; i += 256) lc[i] = 0;
    __syncthreads();
    int tid = blockIdx.x * 256 + threadIdx.x;
    int stride = gridDim.x * 256;
    int n4 = E >> 2;
    for (int j = tid; j < n4; j += stride) {
        int4 d = ((const int4*)edst)[j];
        atomicAdd(&lc[d.x >> NBSH], 1);
        atomicAdd(&lc[d.y >> NBSH], 1);
        atomicAdd(&lc[d.z >> NBSH], 1);
        atomicAdd(&lc[d.w >> NBSH], 1);
    }
    for (int j = (n4 << 2) + tid; j < E; j += stride) atomicAdd(&lc[edst[j] >> NBSH], 1);
    __syncthreads();
    for (int i = threadIdx.x; i < B; i += 256) if (lc[i]) atomicAdd(&bcnt[i], lc[i]);
}

// single-block exclusive scan of bucket counts (B <= 2048)
__global__ __launch_bounds__(1024) void bucket_scan(const int* __restrict__ bcnt,
                                                    int* __restrict__ boff,
                                                    int* __restrict__ bfill, int B, int E) {
    __shared__ int buf[1024];
    int t = threadIdx.x;
    int a = (2 * t     < B) ? bcnt[2 * t]     : 0;
    int b = (2 * t + 1 < B) ? bcnt[2 * t + 1] : 0;
    buf[t] = a + b; __syncthreads();
    for (int d = 1; d < 1024; d <<= 1) {
        int v = (t >= d) ? buf[t - d] : 0; __syncthreads();
        buf[t] += v; __syncthreads();
    }
    int excl = (t == 0) ? 0 : buf[t - 1];
    if (2 * t     < B) { boff[2 * t]     = excl;     bfill[2 * t]     = excl; }
    if (2 * t + 1 < B) { boff[2 * t + 1] = excl + a; bfill[2 * t + 1] = excl + a; }
    if (t == 0) boff[B] = E;
}

// route edges into bucket regions; desc = (src | dstlow<<17, w-bits)
__global__ __launch_bounds__(256) void bucket_scatter(const int* __restrict__ esrc,
                                                      const int* __restrict__ edst,
                                                      const float* __restrict__ ew,
                                                      int* __restrict__ bfill,
                                                      int2* __restrict__ binned, int E) {
    int tid = blockIdx.x * 256 + threadIdx.x;
    int stride = gridDim.x * 256;
    int n4 = E >> 2;
    for (int j = tid; j < n4; j += stride) {
        int4   s = ((const int4*)esrc)[j];
        int4   d = ((const int4*)edst)[j];
        float4 w = ((const float4*)ew)[j];
        int p;
        p = atomicAdd(&bfill[d.x >> NBSH], 1);
        binned[p] = make_int2(s.x | ((d.x & (NPB - 1)) << 17), __float_as_int(w.x));
        p = atomicAdd(&bfill[d.y >> NBSH], 1);
        binned[p] = make_int2(s.y | ((d.y & (NPB - 1)) << 17), __float_as_int(w.y));
        p = atomicAdd(&bfill[d.z >> NBSH], 1);
        binned[p] = make_int2(s.z | ((d.z & (NPB - 1)) << 17), __float_as_int(w.z));
        p = atomicAdd(&bfill[d.w >> NBSH], 1);
        binned[p] = make_int2(s.w | ((d.w & (NPB - 1)) << 17), __float_as_int(w.w));
    }
    for (int j = (n4 << 2) + tid; j < E; j += stride) {
        int dd = edst[j];
        int p = atomicAdd(&bfill[dd >> NBSH], 1);
        binned[p] = make_int2(esrc[j] | ((dd & (NPB - 1)) << 17), __float_as_int(ew[j]));
    }
}

// one block per bucket: 64-node x 128-float accumulator in LDS; fused residual.
// Branchless ILP-8 inner loop: clamp index, zero weight for OOB.
template<bool BF16>
__global__ __launch_bounds__(512) void bucket_gather(const uint* __restrict__ xb,
                                                     const float* __restrict__ x,
                                                     const int* __restrict__ boff,
                                                     const int2* __restrict__ binned,
                                                     float* __restrict__ out, int N) {
    __shared__ float acc[NPB * 128];   // 32 KB
    int b = blockIdx.x;
    int node0 = b << NBSH;

    for (int i = threadIdx.x; i < NPB * 32; i += 512)
        ((float4*)acc)[i] = make_float4(0.f, 0.f, 0.f, 0.f);
    __syncthreads();

    int beg = boff[b], end = boff[b + 1];
    int wid  = threadIdx.x >> 6;
    int lane = threadIdx.x & 63;

    for (int e0 = beg + wid * 8; e0 < end; e0 += 64) {
        int2 dd[8];
        #pragma unroll
        for (int u = 0; u < 8; ++u) {
            int e = e0 + u;
            e = (e < end) ? e : (end - 1);      // clamp, branchless
            dd[u] = binned[e];
        }
        uint  pk[8];
        float va[8], vb[8];
        float wv[8];
        int   dl[8];
        #pragma unroll
        for (int u = 0; u < 8; ++u) {
            int src = dd[u].x & 0x1FFFF;
            dl[u] = (dd[u].x >> 17) & (NPB - 1);
            wv[u] = (e0 + u < end) ? __int_as_float(dd[u].y) : 0.0f;
            if (BF16) {
                pk[u] = xb[(size_t)src * 64 + lane];
            } else {
                va[u] = x[(size_t)src * 128 + lane];
                vb[u] = x[(size_t)src * 128 + lane + 64];
            }
        }
        #pragma unroll
        for (int u = 0; u < 8; ++u) {
            float v0, v1;
            if (BF16) {
                v0 = __uint_as_float(pk[u] << 16);           // elem lane
                v1 = __uint_as_float(pk[u] & 0xFFFF0000u);   // elem lane+64
            } else { v0 = va[u]; v1 = vb[u]; }
            atomicAdd(&acc[dl[u] * 128 + lane],      v0 * wv[u]);
            atomicAdd(&acc[dl[u] * 128 + lane + 64], v1 * wv[u]);
        }
    }
    __syncthreads();

    // epilogue: out = acc + x (residual), coalesced
    int nnodes = min(NPB, N - node0);
    for (int i = threadIdx.x; i < nnodes * 32; i += 512) {
        int node = node0 + (i >> 5);
        int c4   = i & 31;
        float4 r = ((const float4*)(x + (size_t)node * 128))[c4];
        float4 a = ((float4*)acc)[i];
        ((float4*)(out + (size_t)node * 128))[c4] =
            make_float4(a.x + r.x, a.y + r.y, a.z + r.z, a.w + r.w);
    }
}

// ------------------------------------------------- fallback atomic path

__global__ __launch_bounds__(256) void copy_kernel(const float4* __restrict__ src,
                                                   float4* __restrict__ dst, int n4) {
    int i = blockIdx.x * 256 + threadIdx.x;
    if (i < n4) dst[i] = src[i];
}

__global__ __launch_bounds__(256) void scatter_kernel(const float* __restrict__ x,
                                                      const int* __restrict__ esrc,
                                                      const int* __restrict__ edst,
                                                      const float* __restrict__ ew,
                                                      float* __restrict__ agg, int E) {
    int e = blockIdx.x * 8 + (threadIdx.x >> 5);
    if (e >= E) return;
    int lane = threadIdx.x & 31;
    int s = esrc[e];
    int d = edst[e];
    float w = ew[e];
    float4 v = ((const float4*)(x + (size_t)s * 128))[lane];
    float* dp = agg + (size_t)d * 128 + lane * 4;
    atomicAdd(dp + 0, v.x * w);
    atomicAdd(dp + 1, v.y * w);
    atomicAdd(dp + 2, v.z * w);
    atomicAdd(dp + 3, v.w * w);
}

// ----------------------------------------------------------------- GEMM

// out[r,:] = selu(in[r,:] @ W + b); W [128][128] row-major; in-place safe.
__global__ __launch_bounds__(256) void gemm_bias_selu(const float* __restrict__ inp,
                                                      const float* __restrict__ W,
                                                      const float* __restrict__ bias,
                                                      float* __restrict__ outp, int nrows) {
    __shared__ float sW[128 * 128];
    __shared__ float sH[32 * 128];

    float4* sW4 = (float4*)sW;
    float4* sH4 = (float4*)sH;

    for (int i = threadIdx.x; i < 128 * 32; i += 256)
        sW4[i] = ((const float4*)W)[i];

    int row0 = blockIdx.x * 32;
    for (int i = threadIdx.x; i < 32 * 32; i += 256) {
        int r = row0 + (i >> 5);
        sH4[i] = (r < nrows) ? ((const float4*)inp)[(size_t)r * 32 + (i & 31)]
                             : make_float4(0.f, 0.f, 0.f, 0.f);
    }
    __syncthreads();

    int cg = threadIdx.x & 31;
    int rg = (threadIdx.x >> 5) << 2;

    float4 acc[4];
    #pragma unroll
    for (int r = 0; r < 4; ++r) acc[r] = make_float4(0.f, 0.f, 0.f, 0.f);

    #pragma unroll 4
    for (int k4 = 0; k4 < 32; ++k4) {
        float4 w0 = sW4[(k4 * 4 + 0) * 32 + cg];
        float4 w1 = sW4[(k4 * 4 + 1) * 32 + cg];
        float4 w2 = sW4[(k4 * 4 + 2) * 32 + cg];
        float4 w3 = sW4[(k4 * 4 + 3) * 32 + cg];
        #pragma unroll
        for (int r = 0; r < 4; ++r) {
            float4 h = sH4[(rg + r) * 32 + k4];
            acc[r].x = fmaf(h.x, w0.x, fmaf(h.y, w1.x, fmaf(h.z, w2.x, fmaf(h.w, w3.x, acc[r].x))));
            acc[r].y = fmaf(h.x, w0.y, fmaf(h.y, w1.y, fmaf(h.z, w2.y, fmaf(h.w, w3.y, acc[r].y))));
            acc[r].z = fmaf(h.x, w0.z, fmaf(h.y, w1.z, fmaf(h.z, w2.z, fmaf(h.w, w3.z, acc[r].z))));
            acc[r].w = fmaf(h.x, w0.w, fmaf(h.y, w1.w, fmaf(h.z, w2.w, fmaf(h.w, w3.w, acc[r].w))));
        }
    }

    float4 bv = ((const float4*)bias)[cg];
    #pragma unroll
    for (int r = 0; r < 4; ++r) {
        int row = row0 + rg + r;
        if (row < nrows) {
            float4 o;
            o.x = selu_f(acc[r].x + bv.x);
            o.y = selu_f(acc[r].y + bv.y);
            o.z = selu_f(acc[r].z + bv.z);
            o.w = selu_f(acc[r].w + bv.w);
            ((float4*)outp)[(size_t)row * 32 + cg] = o;
        }
    }
}

// ---------------------------------------------------------------- launch

extern "C" void kernel_launch(void* const* d_in, const int* in_sizes, int n_in,
                              void* d_out, int out_size, void* d_ws, size_t ws_size,
                              hipStream_t stream) {
    (void)n_in; (void)out_size;
    const float* x    = (const float*)d_in[0];
    const int*   esrc = (const int*)  d_in[1];
    const int*   edst = (const int*)  d_in[2];
    const float* ew   = (const float*)d_in[3];
    const float* W1   = (const float*)d_in[4];
    const float* b1   = (const float*)d_in[5];
    const float* W2   = (const float*)d_in[6];
    const float* b2   = (const float*)d_in[7];
    float* out = (float*)d_out;

    int N = in_sizes[0] / 128;
    int E = in_sizes[1];
    int B = (N + NPB - 1) >> NBSH;

    // ws layout: bcnt(B) | boff(B+1) | bfill(B) | [align16] xb(N*128*2B) | binned(E*8B)
    size_t hdr   = ((size_t)(3 * B + 1) * 4 + 15) & ~(size_t)15;
    size_t xb_b  = (size_t)N * 256;
    size_t bin_b = (size_t)E * 8;
    size_t need_bf16 = hdr + xb_b + bin_b;
    size_t need_f32  = hdr + bin_b;

    bool use_bf16 = (ws_size >= need_bf16);
    bool use_csr  = (B <= 2048) && (ws_size >= need_f32) && (N <= 131072);

    if (use_csr) {
        int*  bcnt  = (int*)d_ws;
        int*  boff  = bcnt + B;
        int*  bfill = boff + B + 1;
        uint* xb    = (uint*)((char*)d_ws + hdr);
        int2* binned = (int2*)((char*)d_ws + hdr + (use_bf16 ? xb_b : 0));

        hipMemsetAsync(bcnt, 0, (size_t)B * 4, stream);

        if (use_bf16) {
            int total = N * 64;
            to_bf16<<<(total + 255) / 256, 256, 0, stream>>>(x, xb, total);
        }

        int hb = (E / 4 + 255) / 256; if (hb > 2048) hb = 2048;
        bucket_hist<<<hb, 256, 0, stream>>>(edst, bcnt, E, B);
        bucket_scan<<<1, 1024, 0, stream>>>(bcnt, boff, bfill, B, E);
        bucket_scatter<<<hb, 256, 0, stream>>>(esrc, edst, ew, bfill, binned, E);

        if (use_bf16)
            bucket_gather<true><<<B, 512, 0, stream>>>(xb, x, boff, binned, out, N);
        else
            bucket_gather<false><<<B, 512, 0, stream>>>(xb, x, boff, binned, out, N);
    } else {
        int n4 = N * 32;
        copy_kernel<<<(n4 + 255) / 256, 256, 0, stream>>>((const float4*)x, (float4*)out, n4);
        scatter_kernel<<<(E + 7) / 8, 256, 0, stream>>>(x, esrc, edst, ew, out, E);
    }

    // ---- dense layers, in place ----
    int gblocks = (N + 31) / 32;
    gemm_bias_selu<<<gblocks, 256, 0, stream>>>(out, W1, b1, out, N);
    gemm_bias_selu<<<gblocks, 256, 0, stream>>>(out, W2, b2, out, N);
}